// Round 6
// baseline (59773.853 us; speedup 1.0000x reference)
//
#include <hip/hip_runtime.h>
#include <stdint.h>

#define TT 512
#define BB 64
#define MM (BB * TT)  // 32768

typedef short bf16x8 __attribute__((ext_vector_type(8)));
typedef float f32x4  __attribute__((ext_vector_type(4)));
typedef unsigned uint32x4 __attribute__((ext_vector_type(4)));
typedef unsigned uint32x2 __attribute__((ext_vector_type(2)));

#define LNP ((size_t)MM * 1024)  // plane stride for g_ln (elements)

// ---- static device workspace ----
__device__ __align__(256) float g_xg[(size_t)MM * 3072];       // 384 MB fp32 input projections
__device__ __align__(256) unsigned g_hex[88080384];            // 352 MB per-layer h, packed (hi<<16|lo)
__device__ __align__(256) unsigned short g_ln[2 * LNP];        // 128 MB layer input, hi+lo bf16
__device__ __align__(256) unsigned short g_w[18579456];        // 37 MB weights hi+lo bf16
__device__ unsigned g_flags[6 * TT * 64];                      // per-(layer,t,block) done flags

__device__ __forceinline__ float bf2f(unsigned short u) {
  union { unsigned int i; float f; } c; c.i = ((unsigned int)u) << 16; return c.f;
}
__device__ __forceinline__ unsigned short f2bf(float f) {
  union { float f; unsigned int i; } c; c.f = f;
  unsigned int u = c.i;
  return (unsigned short)((u + 0x7FFFu + ((u >> 16) & 1u)) >> 16);
}

__device__ __forceinline__ void gload16(const void* g, void* l) {
  __builtin_amdgcn_global_load_lds(
      (const __attribute__((address_space(1))) unsigned int*)g,
      (__attribute__((address_space(3))) unsigned int*)l, 16, 0, 0);
}

// ---------------- zero the flags ----------------
__global__ void __launch_bounds__(256) k_zero() {
  int i = blockIdx.x * 256 + threadIdx.x;
  int st = gridDim.x * 256;
  for (; i < 6 * TT * 64; i += st) g_flags[i] = 0;
}

// ---------------- f32 -> split bf16 (hi+lo) converts ----------------
__global__ void __launch_bounds__(256) k_cvt_split(const float* __restrict__ s, int n,
                                                   int offh, int offl) {
  int i = blockIdx.x * 256 + threadIdx.x;
  int st = gridDim.x * 256;
  for (; i < n; i += st) {
    float v = s[i];
    unsigned short hi = f2bf(v);
    g_w[offh + i] = hi;
    g_w[offl + i] = f2bf(v - bf2f(hi));
  }
}
__global__ void __launch_bounds__(256) k_cvt_x(const float* __restrict__ s, int n) {
  int i = blockIdx.x * 256 + threadIdx.x;
  int st = gridDim.x * 256;
  for (; i < n; i += st) {
    float v = s[i];
    unsigned short hi = f2bf(v);
    g_ln[i] = hi;
    g_ln[LNP + i] = f2bf(v - bf2f(hi));
  }
}

// ---------------- split-bf16 GEMM  C[M][N] = A[M][K] * B[N][K]^T ----------------
// acc += Ah*Bh + Al*Bh + Ah*Bl   (Al*Bl ~2^-18, dropped)
__global__ void __launch_bounds__(256) k_gemm(int N, int K, int bhoff, int bloff) {
  __shared__ char sm[65536];
  char* Ah = sm;
  char* Al = sm + 16384;
  char* Bh = sm + 32768;
  char* Bl = sm + 49152;
  const unsigned short* A0 = g_ln;
  const unsigned short* A1 = g_ln + LNP;
  const unsigned short* B0 = g_w + bhoff;
  const unsigned short* B1 = g_w + bloff;
  const int tid = threadIdx.x;
  const int lane = tid & 63;
  const int w = tid >> 6;
  const int wm = w >> 1, wn = w & 1;
  const int m0 = blockIdx.x * 128, n0 = blockIdx.y * 128;
  const int c16 = lane & 15, r4 = lane >> 4;

  f32x4 acc[4][4];
#pragma unroll
  for (int i = 0; i < 4; ++i)
#pragma unroll
    for (int j = 0; j < 4; ++j) acc[i][j] = {0.f, 0.f, 0.f, 0.f};

  for (int k0 = 0; k0 < K; k0 += 64) {
    __syncthreads();
#pragma unroll
    for (int i = 0; i < 4; ++i) {
      int c = i * 256 + tid;
      int row = c >> 3, ch = c & 7;
      size_t ao = (size_t)(m0 + row) * K + k0 + ch * 8;
      size_t bo = (size_t)(n0 + row) * K + k0 + ch * 8;
      gload16(A0 + ao, Ah + c * 16);
      gload16(A1 + ao, Al + c * 16);
      gload16(B0 + bo, Bh + c * 16);
      gload16(B1 + bo, Bl + c * 16);
    }
    __syncthreads();
#pragma unroll
    for (int ks = 0; ks < 2; ++ks) {
      bf16x8 avh[4], avl[4], bvh[4], bvl[4];
#pragma unroll
      for (int mt = 0; mt < 4; ++mt) {
        int o = (wm * 64 + mt * 16 + c16) * 128 + ks * 64 + r4 * 16;
        avh[mt] = *(const bf16x8*)(Ah + o);
        avl[mt] = *(const bf16x8*)(Al + o);
      }
#pragma unroll
      for (int nt = 0; nt < 4; ++nt) {
        int o = (wn * 64 + nt * 16 + c16) * 128 + ks * 64 + r4 * 16;
        bvh[nt] = *(const bf16x8*)(Bh + o);
        bvl[nt] = *(const bf16x8*)(Bl + o);
      }
#pragma unroll
      for (int mt = 0; mt < 4; ++mt)
#pragma unroll
        for (int nt = 0; nt < 4; ++nt) {
          acc[mt][nt] = __builtin_amdgcn_mfma_f32_16x16x32_bf16(avh[mt], bvh[nt], acc[mt][nt], 0, 0, 0);
          acc[mt][nt] = __builtin_amdgcn_mfma_f32_16x16x32_bf16(avl[mt], bvh[nt], acc[mt][nt], 0, 0, 0);
          acc[mt][nt] = __builtin_amdgcn_mfma_f32_16x16x32_bf16(avh[mt], bvl[nt], acc[mt][nt], 0, 0, 0);
        }
    }
  }
#pragma unroll
  for (int mt = 0; mt < 4; ++mt)
#pragma unroll
    for (int nt = 0; nt < 4; ++nt) {
      int col = n0 + wn * 64 + nt * 16 + c16;
#pragma unroll
      for (int q = 0; q < 4; ++q) {
        int row = m0 + wm * 64 + mt * 16 + r4 * 4 + q;
        g_xg[(size_t)row * N + col] = acc[mt][nt][q];
      }
    }
}

// ---------------- GRU scan, fence-free coherent exchange ----------------
// Grid = H/16 blocks; block owns 16 h-columns. Whh slice streamed from
// per-XCD L2 (fixed addresses -> stays hot). h exchanged as packed uint32
// (hi<<16|lo) via relaxed agent-scope atomics (write-through / L2-bypass):
// no wbl2/inv fences anywhere in the loop.
template <int H, int NBLK>
__global__ void __launch_bounds__(256) k_scan(int whoff, int wloff, size_t hoff, int coff) {
  constexpr int KI = H / 32;
  unsigned* hexc = g_hex + hoff;
  const int tid = threadIdx.x;
  const int lane = tid & 63;
  const int w = tid >> 6;
  const int bid = blockIdx.x;
  const int jb = bid * 16;
  const int c16 = lane & 15, r4 = lane >> 4;

  // Whh row pointers for this lane's column (B-frag: row = g*H + jb + c16)
  const unsigned short* bh0 = g_w + whoff + ((size_t)(0 * H + jb + c16)) * H + r4 * 8;
  const unsigned short* bh1 = g_w + whoff + ((size_t)(1 * H + jb + c16)) * H + r4 * 8;
  const unsigned short* bh2 = g_w + whoff + ((size_t)(2 * H + jb + c16)) * H + r4 * 8;
  const long wld = (long)wloff - (long)whoff;  // element delta hi->lo plane

  const int arow = w * 16 + c16;  // A-frag batch row for this lane

  float hprev[4] = {0.f, 0.f, 0.f, 0.f};

  for (int t = 0; t < TT; ++t) {
    // prefetch xg[t] (independent of the t-1 sync)
    float xr[4], xz[4], xn[4];
#pragma unroll
    for (int q = 0; q < 4; ++q) {
      int b = w * 16 + r4 * 4 + q;
      size_t xo = ((size_t)b * TT + t) * (3 * H) + jb + c16;
      xr[q] = g_xg[xo];
      xz[q] = g_xg[xo + H];
      xn[q] = g_xg[xo + 2 * H];
    }

    f32x4 acc[3];
#pragma unroll
    for (int g = 0; g < 3; ++g) acc[g] = {0.f, 0.f, 0.f, 0.f};

    if (t > 0) {
      if (tid < 64) {
        const unsigned* fl = g_flags + (size_t)(coff + t - 1) * 64;
        unsigned v;
        do {
          v = (lane < NBLK)
              ? __hip_atomic_load(fl + lane, __ATOMIC_RELAXED, __HIP_MEMORY_SCOPE_AGENT)
              : 1u;
        } while (__any(v == 0));
      }
      __syncthreads();

      const unsigned long long* ap = reinterpret_cast<const unsigned long long*>(
          hexc + ((size_t)(t - 1) * BB + arow) * H + r4 * 8);
#pragma unroll 4
      for (int ki = 0; ki < KI; ++ki) {
        unsigned long long d0 = __hip_atomic_load(ap + ki * 16 + 0, __ATOMIC_RELAXED, __HIP_MEMORY_SCOPE_AGENT);
        unsigned long long d1 = __hip_atomic_load(ap + ki * 16 + 1, __ATOMIC_RELAXED, __HIP_MEMORY_SCOPE_AGENT);
        unsigned long long d2 = __hip_atomic_load(ap + ki * 16 + 2, __ATOMIC_RELAXED, __HIP_MEMORY_SCOPE_AGENT);
        unsigned long long d3 = __hip_atomic_load(ap + ki * 16 + 3, __ATOMIC_RELAXED, __HIP_MEMORY_SCOPE_AGENT);
        unsigned u0 = (unsigned)d0, u1 = (unsigned)(d0 >> 32);
        unsigned u2 = (unsigned)d1, u3 = (unsigned)(d1 >> 32);
        unsigned u4 = (unsigned)d2, u5 = (unsigned)(d2 >> 32);
        unsigned u6 = (unsigned)d3, u7 = (unsigned)(d3 >> 32);
        union { uint32x4 u; bf16x8 v; } ch, cl;
        ch.u[0] = (u1 & 0xffff0000u) | (u0 >> 16);
        ch.u[1] = (u3 & 0xffff0000u) | (u2 >> 16);
        ch.u[2] = (u5 & 0xffff0000u) | (u4 >> 16);
        ch.u[3] = (u7 & 0xffff0000u) | (u6 >> 16);
        cl.u[0] = (u1 << 16) | (u0 & 0xffffu);
        cl.u[1] = (u3 << 16) | (u2 & 0xffffu);
        cl.u[2] = (u5 << 16) | (u4 & 0xffffu);
        cl.u[3] = (u7 << 16) | (u6 & 0xffffu);
        bf16x8 ah = ch.v, al = cl.v;

        bf16x8 b0h = *(const bf16x8*)(bh0 + ki * 32);
        bf16x8 b0l = *(const bf16x8*)(bh0 + wld + ki * 32);
        acc[0] = __builtin_amdgcn_mfma_f32_16x16x32_bf16(ah, b0h, acc[0], 0, 0, 0);
        acc[0] = __builtin_amdgcn_mfma_f32_16x16x32_bf16(al, b0h, acc[0], 0, 0, 0);
        acc[0] = __builtin_amdgcn_mfma_f32_16x16x32_bf16(ah, b0l, acc[0], 0, 0, 0);
        bf16x8 b1h = *(const bf16x8*)(bh1 + ki * 32);
        bf16x8 b1l = *(const bf16x8*)(bh1 + wld + ki * 32);
        acc[1] = __builtin_amdgcn_mfma_f32_16x16x32_bf16(ah, b1h, acc[1], 0, 0, 0);
        acc[1] = __builtin_amdgcn_mfma_f32_16x16x32_bf16(al, b1h, acc[1], 0, 0, 0);
        acc[1] = __builtin_amdgcn_mfma_f32_16x16x32_bf16(ah, b1l, acc[1], 0, 0, 0);
        bf16x8 b2h = *(const bf16x8*)(bh2 + ki * 32);
        bf16x8 b2l = *(const bf16x8*)(bh2 + wld + ki * 32);
        acc[2] = __builtin_amdgcn_mfma_f32_16x16x32_bf16(ah, b2h, acc[2], 0, 0, 0);
        acc[2] = __builtin_amdgcn_mfma_f32_16x16x32_bf16(al, b2h, acc[2], 0, 0, 0);
        acc[2] = __builtin_amdgcn_mfma_f32_16x16x32_bf16(ah, b2l, acc[2], 0, 0, 0);
      }
    }

#pragma unroll
    for (int q = 0; q < 4; ++q) {
      int b = w * 16 + r4 * 4 + q;
      float rg = 1.f / (1.f + __expf(-(xr[q] + acc[0][q])));
      float zg = 1.f / (1.f + __expf(-(xz[q] + acc[1][q])));
      float ng = tanhf(xn[q] + rg * acc[2][q]);
      float h = (1.f - zg) * ng + zg * hprev[q];
      hprev[q] = h;
      unsigned short hi = f2bf(h);
      unsigned short lo = f2bf(h - bf2f(hi));
      unsigned pu = ((unsigned)hi << 16) | (unsigned)lo;
      __hip_atomic_store(hexc + ((size_t)t * BB + b) * H + jb + c16, pu,
                         __ATOMIC_RELAXED, __HIP_MEMORY_SCOPE_AGENT);
    }
    __builtin_amdgcn_s_waitcnt(0);
    __syncthreads();
    if (tid == 0)
      __hip_atomic_store(g_flags + (size_t)(coff + t) * 64 + bid, 1u,
                         __ATOMIC_RELAXED, __HIP_MEMORY_SCOPE_AGENT);
  }
}

// ---------------- LayerNorm (eps=0): reads packed hex, row r = b*T+t ----------------
template <int H, bool LAST>
__global__ void __launch_bounds__(256) k_ln(const float* __restrict__ gw,
                                            const float* __restrict__ bw,
                                            float* __restrict__ of32,
                                            size_t hoff) {
  const int r = blockIdx.x * 4 + (threadIdx.x >> 6);
  const int lane = threadIdx.x & 63;
  const int b = r >> 9;
  const int t = r & 511;
  const unsigned* row = g_hex + hoff + ((size_t)t * BB + b) * H;
  constexpr int E = H / 64;
  float x[E];
  if constexpr (E >= 4) {
#pragma unroll
    for (int j = 0; j < E / 4; ++j) {
      uint32x4 v = *(const uint32x4*)(row + lane * E + 4 * j);
#pragma unroll
      for (int e = 0; e < 4; ++e)
        x[4 * j + e] = bf2f((unsigned short)(v[e] >> 16)) + bf2f((unsigned short)(v[e] & 0xffffu));
    }
  } else {
    uint32x2 v = *(const uint32x2*)(row + lane * 2);
    x[0] = bf2f((unsigned short)(v[0] >> 16)) + bf2f((unsigned short)(v[0] & 0xffffu));
    x[1] = bf2f((unsigned short)(v[1] >> 16)) + bf2f((unsigned short)(v[1] & 0xffffu));
  }
  float s = 0.f;
#pragma unroll
  for (int e = 0; e < E; ++e) s += x[e];
#pragma unroll
  for (int m = 1; m < 64; m <<= 1) s += __shfl_xor(s, m);
  const float mean = s * (1.f / H);
  float vs = 0.f;
#pragma unroll
  for (int e = 0; e < E; ++e) { float d = x[e] - mean; vs += d * d; }
#pragma unroll
  for (int m = 1; m < 64; m <<= 1) vs += __shfl_xor(vs, m);
  const float rstd = rsqrtf(vs * (1.f / H));
#pragma unroll
  for (int e = 0; e < E; ++e) {
    int col = lane * E + e;
    float y = (x[e] - mean) * rstd * gw[col] + bw[col];
    if constexpr (LAST) {
      of32[(size_t)r * H + col] = y;
    } else {
      unsigned short hi = f2bf(y);
      g_ln[(size_t)r * H + col] = hi;
      g_ln[LNP + (size_t)r * H + col] = f2bf(y - bf2f(hi));
    }
  }
}

extern "C" void kernel_launch(void* const* d_in, const int* in_sizes, int n_in,
                              void* d_out, int out_size, void* d_ws, size_t ws_size,
                              hipStream_t stream) {
  (void)in_sizes; (void)n_in; (void)out_size; (void)d_ws; (void)ws_size;
  static const int DIN[6] = {128, 256, 512, 1024, 512, 256};
  static const int HS[6]  = {256, 512, 1024, 512, 256, 128};
  const int M = MM;

  // packed weight offsets (elements)
  int wihh_off[6], wihl_off[6], whhh_off[6], whhl_off[6];
  size_t hex_off[6];
  {
    int off = 0;
    size_t hoff = 0;
    for (int l = 0; l < 6; ++l) {
      int sih = 3 * HS[l] * DIN[l], shh = 3 * HS[l] * HS[l];
      wihh_off[l] = off; off += sih;
      wihl_off[l] = off; off += sih;
      whhh_off[l] = off; off += shh;
      whhl_off[l] = off; off += shh;
      hex_off[l] = hoff; hoff += (size_t)TT * BB * HS[l];
    }
  }

  k_zero<<<384, 256, 0, stream>>>();
  k_cvt_x<<<1024, 256, 0, stream>>>((const float*)d_in[0], M * 128);
  for (int l = 0; l < 6; ++l) {
    k_cvt_split<<<512, 256, 0, stream>>>((const float*)d_in[1 + 4 * l], 3 * HS[l] * DIN[l],
                                         wihh_off[l], wihl_off[l]);
    k_cvt_split<<<512, 256, 0, stream>>>((const float*)d_in[2 + 4 * l], 3 * HS[l] * HS[l],
                                         whhh_off[l], whhl_off[l]);
  }

  for (int l = 0; l < 6; ++l) {
    const int H = HS[l], K = DIN[l], N = 3 * H;
    dim3 gg(M / 128, N / 128);
    k_gemm<<<gg, 256, 0, stream>>>(N, K, wihh_off[l], wihl_off[l]);

    const int coff = l * TT;
    switch (H) {
      case 1024: k_scan<1024, 64><<<64, 256, 0, stream>>>(whhh_off[l], whhl_off[l], hex_off[l], coff); break;
      case 512:  k_scan<512, 32><<<32, 256, 0, stream>>>(whhh_off[l], whhl_off[l], hex_off[l], coff); break;
      case 256:  k_scan<256, 16><<<16, 256, 0, stream>>>(whhh_off[l], whhl_off[l], hex_off[l], coff); break;
      case 128:  k_scan<128, 8><<<8, 256, 0, stream>>>(whhh_off[l], whhl_off[l], hex_off[l], coff); break;
    }

    const float* gp = (const float*)d_in[3 + 4 * l];
    const float* bp = (const float*)d_in[4 + 4 * l];
    if (l == 5) {
      k_ln<128, true><<<M / 4, 256, 0, stream>>>(gp, bp, (float*)d_out, hex_off[l]);
    } else {
      switch (H) {
        case 1024: k_ln<1024, false><<<M / 4, 256, 0, stream>>>(gp, bp, nullptr, hex_off[l]); break;
        case 512:  k_ln<512, false><<<M / 4, 256, 0, stream>>>(gp, bp, nullptr, hex_off[l]); break;
        case 256:  k_ln<256, false><<<M / 4, 256, 0, stream>>>(gp, bp, nullptr, hex_off[l]); break;
      }
    }
  }
}

// Round 7
// 45582.599 us; speedup vs baseline: 1.3113x; 1.3113x over previous
//
#include <hip/hip_runtime.h>
#include <stdint.h>

#define TT 512
#define BB 64
#define MM (BB * TT)  // 32768

typedef short bf16x8 __attribute__((ext_vector_type(8)));
typedef float f32x4  __attribute__((ext_vector_type(4)));
typedef unsigned uint32x4 __attribute__((ext_vector_type(4)));
typedef unsigned uint32x2 __attribute__((ext_vector_type(2)));

#define LNP ((size_t)MM * 1024)  // plane stride for g_ln (elements)
#define HEXN 88080384u           // total hex u32 elements (352 MB)

// ---- static device workspace ----
__device__ __align__(256) float g_xg[(size_t)MM * 3072];       // 384 MB fp32 input projections
__device__ __align__(256) unsigned g_hex[HEXN];                // per-layer h, packed (hi<<16|lo), write-once
__device__ __align__(256) unsigned short g_ln[2 * LNP];        // 128 MB layer input, hi+lo bf16
__device__ __align__(256) unsigned short g_w[18579456];        // 37 MB weights hi+lo bf16

__device__ __forceinline__ float bf2f(unsigned short u) {
  union { unsigned int i; float f; } c; c.i = ((unsigned int)u) << 16; return c.f;
}
__device__ __forceinline__ unsigned short f2bf(float f) {
  union { float f; unsigned int i; } c; c.f = f;
  unsigned int u = c.i;
  return (unsigned short)((u + 0x7FFFu + ((u >> 16) & 1u)) >> 16);
}

__device__ __forceinline__ void gload16(const void* g, void* l) {
  __builtin_amdgcn_global_load_lds(
      (const __attribute__((address_space(1))) unsigned int*)g,
      (__attribute__((address_space(3))) unsigned int*)l, 16, 0, 0);
}

// coherent (L2-bypass) 16B load: retry path only
__device__ __forceinline__ uint32x4 scload4(const unsigned* p) {
  uint32x4 r;
  asm volatile("global_load_dwordx4 %0, %1, off sc0 sc1\n\ts_waitcnt vmcnt(0)"
               : "=&v"(r) : "v"(p) : "memory");
  return r;
}
// write-through store (visible at L3 without L2 flush)
__device__ __forceinline__ void scstore(unsigned* p, unsigned v) {
  asm volatile("global_store_dword %0, %1, off sc0 sc1" :: "v"(p), "v"(v) : "memory");
}
__device__ __forceinline__ bool has_sent(uint32x4 a, uint32x4 b) {
  bool bad = false;
#pragma unroll
  for (int e = 0; e < 4; ++e) bad = bad || (a[e] == 0xFFFFFFFFu) || (b[e] == 0xFFFFFFFFu);
  return bad;
}

// ---------------- zap hex to sentinel ----------------
__global__ void __launch_bounds__(256) k_zap() {
  const unsigned v = 0xFFFFFFFFu;
  uint32x4 q = {v, v, v, v};
  size_t i = (size_t)blockIdx.x * 256 + threadIdx.x;
  size_t st = (size_t)gridDim.x * 256;
  size_t n4 = HEXN / 4;
  for (; i < n4; i += st) ((uint32x4*)g_hex)[i] = q;
}

// ---------------- f32 -> split bf16 (hi+lo) converts ----------------
__global__ void __launch_bounds__(256) k_cvt_split(const float* __restrict__ s, int n,
                                                   int offh, int offl) {
  int i = blockIdx.x * 256 + threadIdx.x;
  int st = gridDim.x * 256;
  for (; i < n; i += st) {
    float v = s[i];
    unsigned short hi = f2bf(v);
    g_w[offh + i] = hi;
    g_w[offl + i] = f2bf(v - bf2f(hi));
  }
}
__global__ void __launch_bounds__(256) k_cvt_x(const float* __restrict__ s, int n) {
  int i = blockIdx.x * 256 + threadIdx.x;
  int st = gridDim.x * 256;
  for (; i < n; i += st) {
    float v = s[i];
    unsigned short hi = f2bf(v);
    g_ln[i] = hi;
    g_ln[LNP + i] = f2bf(v - bf2f(hi));
  }
}

// ---------------- split-bf16 GEMM  C[M][N] = A[M][K] * B[N][K]^T ----------------
// acc += Ah*Bh + Al*Bh + Ah*Bl   (Al*Bl ~2^-18, dropped)
__global__ void __launch_bounds__(256) k_gemm(int N, int K, int bhoff, int bloff) {
  __shared__ char sm[65536];
  char* Ah = sm;
  char* Al = sm + 16384;
  char* Bh = sm + 32768;
  char* Bl = sm + 49152;
  const unsigned short* A0 = g_ln;
  const unsigned short* A1 = g_ln + LNP;
  const unsigned short* B0 = g_w + bhoff;
  const unsigned short* B1 = g_w + bloff;
  const int tid = threadIdx.x;
  const int lane = tid & 63;
  const int w = tid >> 6;
  const int wm = w >> 1, wn = w & 1;
  const int m0 = blockIdx.x * 128, n0 = blockIdx.y * 128;
  const int c16 = lane & 15, r4 = lane >> 4;

  f32x4 acc[4][4];
#pragma unroll
  for (int i = 0; i < 4; ++i)
#pragma unroll
    for (int j = 0; j < 4; ++j) acc[i][j] = {0.f, 0.f, 0.f, 0.f};

  for (int k0 = 0; k0 < K; k0 += 64) {
    __syncthreads();
#pragma unroll
    for (int i = 0; i < 4; ++i) {
      int c = i * 256 + tid;
      int row = c >> 3, ch = c & 7;
      size_t ao = (size_t)(m0 + row) * K + k0 + ch * 8;
      size_t bo = (size_t)(n0 + row) * K + k0 + ch * 8;
      gload16(A0 + ao, Ah + c * 16);
      gload16(A1 + ao, Al + c * 16);
      gload16(B0 + bo, Bh + c * 16);
      gload16(B1 + bo, Bl + c * 16);
    }
    __syncthreads();
#pragma unroll
    for (int ks = 0; ks < 2; ++ks) {
      bf16x8 avh[4], avl[4], bvh[4], bvl[4];
#pragma unroll
      for (int mt = 0; mt < 4; ++mt) {
        int o = (wm * 64 + mt * 16 + c16) * 128 + ks * 64 + r4 * 16;
        avh[mt] = *(const bf16x8*)(Ah + o);
        avl[mt] = *(const bf16x8*)(Al + o);
      }
#pragma unroll
      for (int nt = 0; nt < 4; ++nt) {
        int o = (wn * 64 + nt * 16 + c16) * 128 + ks * 64 + r4 * 16;
        bvh[nt] = *(const bf16x8*)(Bh + o);
        bvl[nt] = *(const bf16x8*)(Bl + o);
      }
#pragma unroll
      for (int mt = 0; mt < 4; ++mt)
#pragma unroll
        for (int nt = 0; nt < 4; ++nt) {
          acc[mt][nt] = __builtin_amdgcn_mfma_f32_16x16x32_bf16(avh[mt], bvh[nt], acc[mt][nt], 0, 0, 0);
          acc[mt][nt] = __builtin_amdgcn_mfma_f32_16x16x32_bf16(avl[mt], bvh[nt], acc[mt][nt], 0, 0, 0);
          acc[mt][nt] = __builtin_amdgcn_mfma_f32_16x16x32_bf16(avh[mt], bvl[nt], acc[mt][nt], 0, 0, 0);
        }
    }
  }
#pragma unroll
  for (int mt = 0; mt < 4; ++mt)
#pragma unroll
    for (int nt = 0; nt < 4; ++nt) {
      int col = n0 + wn * 64 + nt * 16 + c16;
#pragma unroll
      for (int q = 0; q < 4; ++q) {
        int row = m0 + wm * 64 + mt * 16 + r4 * 4 + q;
        g_xg[(size_t)row * N + col] = acc[mt][nt][q];
      }
    }
}

// ---------------- GRU scan: data-flow sync via sentinels ----------------
// Grid = H/16 blocks; block owns 16 h-columns, no flags/barriers. Producers
// write-through (sc0 sc1); consumers use plain cached loads (addresses are
// write-once so a cold L2 miss fetches fresh L3 data) + per-u32 sentinel
// check with sc-bypass retry. Whh slice stays hot in the per-XCD L2.
template <int H, int NBLK>
__global__ void __launch_bounds__(256) k_scan(int whoff, int wloff, size_t hoff) {
  constexpr int KI = H / 32;
  unsigned* hexc = g_hex + hoff;
  const int tid = threadIdx.x;
  const int lane = tid & 63;
  const int w = tid >> 6;
  const int bid = blockIdx.x;
  const int jb = bid * 16;
  const int c16 = lane & 15, r4 = lane >> 4;

  const unsigned short* bh0 = g_w + whoff + ((size_t)(0 * H + jb + c16)) * H + r4 * 8;
  const unsigned short* bh1 = g_w + whoff + ((size_t)(1 * H + jb + c16)) * H + r4 * 8;
  const unsigned short* bh2 = g_w + whoff + ((size_t)(2 * H + jb + c16)) * H + r4 * 8;
  const long wld = (long)wloff - (long)whoff;  // element delta hi->lo plane

  const int arow = w * 16 + c16;  // A-frag batch row for this lane

  float hprev[4] = {0.f, 0.f, 0.f, 0.f};

  for (int t = 0; t < TT; ++t) {
    // xg prefetch (independent of h availability); nt to protect weight L2 set
    float xr[4], xz[4], xn[4];
#pragma unroll
    for (int q = 0; q < 4; ++q) {
      int b = w * 16 + r4 * 4 + q;
      size_t xo = ((size_t)b * TT + t) * (3 * H) + jb + c16;
      xr[q] = __builtin_nontemporal_load(&g_xg[xo]);
      xz[q] = __builtin_nontemporal_load(&g_xg[xo + H]);
      xn[q] = __builtin_nontemporal_load(&g_xg[xo + 2 * H]);
    }

    f32x4 acc[3];
#pragma unroll
    for (int g = 0; g < 3; ++g) acc[g] = {0.f, 0.f, 0.f, 0.f};

    if (t > 0) {
      const unsigned* ap = hexc + ((size_t)(t - 1) * BB + arow) * H + r4 * 8;
#pragma unroll 4
      for (int ki = 0; ki < KI; ++ki) {
        uint32x4 p0 = *(const uint32x4*)(ap + ki * 32);
        uint32x4 p1 = *(const uint32x4*)(ap + ki * 32 + 4);
        if (__builtin_expect(has_sent(p0, p1), 0)) {
          do {
            p0 = scload4(ap + ki * 32);
            p1 = scload4(ap + ki * 32 + 4);
          } while (has_sent(p0, p1));
        }
        union { uint32x4 u; bf16x8 v; } ch, cl;
        ch.u[0] = (p0[1] & 0xffff0000u) | (p0[0] >> 16);
        ch.u[1] = (p0[3] & 0xffff0000u) | (p0[2] >> 16);
        ch.u[2] = (p1[1] & 0xffff0000u) | (p1[0] >> 16);
        ch.u[3] = (p1[3] & 0xffff0000u) | (p1[2] >> 16);
        cl.u[0] = (p0[1] << 16) | (p0[0] & 0xffffu);
        cl.u[1] = (p0[3] << 16) | (p0[2] & 0xffffu);
        cl.u[2] = (p1[1] << 16) | (p1[0] & 0xffffu);
        cl.u[3] = (p1[3] << 16) | (p1[2] & 0xffffu);
        bf16x8 ah = ch.v, al = cl.v;

        bf16x8 b0h = *(const bf16x8*)(bh0 + ki * 32);
        bf16x8 b0l = *(const bf16x8*)(bh0 + wld + ki * 32);
        acc[0] = __builtin_amdgcn_mfma_f32_16x16x32_bf16(ah, b0h, acc[0], 0, 0, 0);
        acc[0] = __builtin_amdgcn_mfma_f32_16x16x32_bf16(al, b0h, acc[0], 0, 0, 0);
        acc[0] = __builtin_amdgcn_mfma_f32_16x16x32_bf16(ah, b0l, acc[0], 0, 0, 0);
        bf16x8 b1h = *(const bf16x8*)(bh1 + ki * 32);
        bf16x8 b1l = *(const bf16x8*)(bh1 + wld + ki * 32);
        acc[1] = __builtin_amdgcn_mfma_f32_16x16x32_bf16(ah, b1h, acc[1], 0, 0, 0);
        acc[1] = __builtin_amdgcn_mfma_f32_16x16x32_bf16(al, b1h, acc[1], 0, 0, 0);
        acc[1] = __builtin_amdgcn_mfma_f32_16x16x32_bf16(ah, b1l, acc[1], 0, 0, 0);
        bf16x8 b2h = *(const bf16x8*)(bh2 + ki * 32);
        bf16x8 b2l = *(const bf16x8*)(bh2 + wld + ki * 32);
        acc[2] = __builtin_amdgcn_mfma_f32_16x16x32_bf16(ah, b2h, acc[2], 0, 0, 0);
        acc[2] = __builtin_amdgcn_mfma_f32_16x16x32_bf16(al, b2h, acc[2], 0, 0, 0);
        acc[2] = __builtin_amdgcn_mfma_f32_16x16x32_bf16(ah, b2l, acc[2], 0, 0, 0);
      }
    }

#pragma unroll
    for (int q = 0; q < 4; ++q) {
      int b = w * 16 + r4 * 4 + q;
      float rg = 1.f / (1.f + __expf(-(xr[q] + acc[0][q])));
      float zg = 1.f / (1.f + __expf(-(xz[q] + acc[1][q])));
      float ng = tanhf(xn[q] + rg * acc[2][q]);
      float h = (1.f - zg) * ng + zg * hprev[q];
      hprev[q] = h;
      unsigned short hi = f2bf(h);
      unsigned short lo = f2bf(h - bf2f(hi));
      scstore(hexc + ((size_t)t * BB + b) * H + jb + c16, ((unsigned)hi << 16) | (unsigned)lo);
    }
  }
}

// ---------------- LayerNorm (eps=0): reads packed hex, row r = b*T+t ----------------
template <int H, bool LAST>
__global__ void __launch_bounds__(256) k_ln(const float* __restrict__ gw,
                                            const float* __restrict__ bw,
                                            float* __restrict__ of32,
                                            size_t hoff) {
  const int r = blockIdx.x * 4 + (threadIdx.x >> 6);
  const int lane = threadIdx.x & 63;
  const int b = r >> 9;
  const int t = r & 511;
  const unsigned* row = g_hex + hoff + ((size_t)t * BB + b) * H;
  constexpr int E = H / 64;
  float x[E];
  if constexpr (E >= 4) {
#pragma unroll
    for (int j = 0; j < E / 4; ++j) {
      uint32x4 v = *(const uint32x4*)(row + lane * E + 4 * j);
#pragma unroll
      for (int e = 0; e < 4; ++e)
        x[4 * j + e] = bf2f((unsigned short)(v[e] >> 16)) + bf2f((unsigned short)(v[e] & 0xffffu));
    }
  } else {
    uint32x2 v = *(const uint32x2*)(row + lane * 2);
    x[0] = bf2f((unsigned short)(v[0] >> 16)) + bf2f((unsigned short)(v[0] & 0xffffu));
    x[1] = bf2f((unsigned short)(v[1] >> 16)) + bf2f((unsigned short)(v[1] & 0xffffu));
  }
  float s = 0.f;
#pragma unroll
  for (int e = 0; e < E; ++e) s += x[e];
#pragma unroll
  for (int m = 1; m < 64; m <<= 1) s += __shfl_xor(s, m);
  const float mean = s * (1.f / H);
  float vs = 0.f;
#pragma unroll
  for (int e = 0; e < E; ++e) { float d = x[e] - mean; vs += d * d; }
#pragma unroll
  for (int m = 1; m < 64; m <<= 1) vs += __shfl_xor(vs, m);
  const float rstd = rsqrtf(vs * (1.f / H));
#pragma unroll
  for (int e = 0; e < E; ++e) {
    int col = lane * E + e;
    float y = (x[e] - mean) * rstd * gw[col] + bw[col];
    if constexpr (LAST) {
      of32[(size_t)r * H + col] = y;
    } else {
      unsigned short hi = f2bf(y);
      g_ln[(size_t)r * H + col] = hi;
      g_ln[LNP + (size_t)r * H + col] = f2bf(y - bf2f(hi));
    }
  }
}

extern "C" void kernel_launch(void* const* d_in, const int* in_sizes, int n_in,
                              void* d_out, int out_size, void* d_ws, size_t ws_size,
                              hipStream_t stream) {
  (void)in_sizes; (void)n_in; (void)out_size; (void)d_ws; (void)ws_size;
  static const int DIN[6] = {128, 256, 512, 1024, 512, 256};
  static const int HS[6]  = {256, 512, 1024, 512, 256, 128};
  const int M = MM;

  // packed weight offsets (elements)
  int wihh_off[6], wihl_off[6], whhh_off[6], whhl_off[6];
  size_t hex_off[6];
  {
    int off = 0;
    size_t hoff = 0;
    for (int l = 0; l < 6; ++l) {
      int sih = 3 * HS[l] * DIN[l], shh = 3 * HS[l] * HS[l];
      wihh_off[l] = off; off += sih;
      wihl_off[l] = off; off += sih;
      whhh_off[l] = off; off += shh;
      whhl_off[l] = off; off += shh;
      hex_off[l] = hoff; hoff += (size_t)TT * BB * HS[l];
    }
  }

  k_zap<<<2048, 256, 0, stream>>>();
  k_cvt_x<<<1024, 256, 0, stream>>>((const float*)d_in[0], M * 128);
  for (int l = 0; l < 6; ++l) {
    k_cvt_split<<<512, 256, 0, stream>>>((const float*)d_in[1 + 4 * l], 3 * HS[l] * DIN[l],
                                         wihh_off[l], wihl_off[l]);
    k_cvt_split<<<512, 256, 0, stream>>>((const float*)d_in[2 + 4 * l], 3 * HS[l] * HS[l],
                                         whhh_off[l], whhl_off[l]);
  }

  for (int l = 0; l < 6; ++l) {
    const int H = HS[l], K = DIN[l], N = 3 * H;
    dim3 gg(M / 128, N / 128);
    k_gemm<<<gg, 256, 0, stream>>>(N, K, wihh_off[l], wihl_off[l]);

    switch (H) {
      case 1024: k_scan<1024, 64><<<64, 256, 0, stream>>>(whhh_off[l], whhl_off[l], hex_off[l]); break;
      case 512:  k_scan<512, 32><<<32, 256, 0, stream>>>(whhh_off[l], whhl_off[l], hex_off[l]); break;
      case 256:  k_scan<256, 16><<<16, 256, 0, stream>>>(whhh_off[l], whhl_off[l], hex_off[l]); break;
      case 128:  k_scan<128, 8><<<8, 256, 0, stream>>>(whhh_off[l], whhl_off[l], hex_off[l]); break;
    }

    const float* gp = (const float*)d_in[3 + 4 * l];
    const float* bp = (const float*)d_in[4 + 4 * l];
    if (l == 5) {
      k_ln<128, true><<<M / 4, 256, 0, stream>>>(gp, bp, (float*)d_out, hex_off[l]);
    } else {
      switch (H) {
        case 1024: k_ln<1024, false><<<M / 4, 256, 0, stream>>>(gp, bp, nullptr, hex_off[l]); break;
        case 512:  k_ln<512, false><<<M / 4, 256, 0, stream>>>(gp, bp, nullptr, hex_off[l]); break;
        case 256:  k_ln<256, false><<<M / 4, 256, 0, stream>>>(gp, bp, nullptr, hex_off[l]); break;
      }
    }
  }
}